// Round 1
// baseline (83.489 us; speedup 1.0000x reference)
//
#include <hip/hip_runtime.h>

// Problem constants (from reference): N=16, C=256, K=6, M=22, Ho=17
#define NB   16
#define CC   256
#define KK   6
#define MM   22
#define HO   17           // M - K + 1
#define NPQ  (HO*HO)      // 289 outputs per batch image
#define TOT  (NB*NPQ)     // 4624 total outputs
#define CHN  8            // channels per block in kernel A
#define CGRP (CC/CHN)     // 32 channel-groups
#define XPC  (MM*MM)      // 484 x-elements per channel
#define ZPC  (KK*KK)      // 36 z-elements per channel

// Kernel A: per-(batch, channel-group) partial correlation.
// mean_coeff*36 accumulated into acc[n*NPQ + pq] via atomics.
__global__ __launch_bounds__(256) void corr_kernel(
    const float* __restrict__ z, const float* __restrict__ x,
    const float* __restrict__ w, float* __restrict__ acc)
{
    __shared__ float szw[CHN * ZPC];   // w_c * sqrt(z)
    __shared__ float sx [CHN * XPC];   // sqrt(x)

    const int b  = blockIdx.x;
    const int n  = b >> 5;             // b / CGRP
    const int cg = b & 31;             // b % CGRP
    const int c0 = cg * CHN;
    const int t  = threadIdx.x;

    const float* zb = z + (size_t)(n * CC + c0) * ZPC;
    const float* xb = x + (size_t)(n * CC + c0) * XPC;

    // Stage w*sqrt(z): 288 contiguous floats
    for (int e = t; e < CHN * ZPC; e += 256) {
        int c = e / ZPC;
        szw[e] = sqrtf(zb[e]) * w[c0 + c];
    }
    // Stage sqrt(x): 3872 contiguous floats, float4-vectorized (base 16B-aligned)
    {
        const float4* xb4 = reinterpret_cast<const float4*>(xb);
        float4* sx4 = reinterpret_cast<float4*>(sx);
        for (int e = t; e < CHN * XPC / 4; e += 256) {
            float4 val = xb4[e];
            float4 o;
            o.x = sqrtf(val.x); o.y = sqrtf(val.y);
            o.z = sqrtf(val.z); o.w = sqrtf(val.w);
            sx4[e] = o;
        }
    }
    __syncthreads();

    // Each thread: outputs pq0 = t (always valid) and pq1 = t+256 (valid if <289).
    // z-value is wave-uniform -> LDS broadcast, shared between the two strips.
    const int pq0 = t;
    const int pq1 = t + 256;
    const int pq1c = (pq1 < NPQ) ? pq1 : (NPQ - 1);
    const int p0 = pq0 / HO, q0 = pq0 % HO;
    const int p1 = pq1c / HO, q1 = pq1c % HO;

    float s0 = 0.f, s1 = 0.f;
    #pragma unroll 1
    for (int ch = 0; ch < CHN; ++ch) {
        const float* zz = szw + ch * ZPC;
        const float* x0 = sx + ch * XPC + p0 * MM + q0;
        const float* x1 = sx + ch * XPC + p1 * MM + q1;
        #pragma unroll
        for (int i = 0; i < KK; ++i) {
            #pragma unroll
            for (int j = 0; j < KK; ++j) {
                float zv = zz[i * KK + j];
                s0 += zv * x0[i * MM + j];
                s1 += zv * x1[i * MM + j];
            }
        }
    }
    atomicAdd(&acc[n * NPQ + pq0], s0);
    if (pq1 < NPQ) atomicAdd(&acc[n * NPQ + pq1], s1);
}

// Kernel B: global BatchNorm (training mode) over all 4624 values + write out.
// Two-pass mean/variance for accuracy.
__global__ __launch_bounds__(512) void bn_kernel(
    const float* __restrict__ acc, const float* __restrict__ bnw,
    const float* __restrict__ bnb, float* __restrict__ out)
{
    __shared__ float sh[8];
    __shared__ float stat[2];
    const int t = threadIdx.x;

    float v[10];
    int nv = 0;
    float sum = 0.f;
    for (int idx = t; idx < TOT; idx += 512) {
        float val = acc[idx] * (1.0f / 36.0f);
        v[nv++] = val;
        sum += val;
    }
    #pragma unroll
    for (int off = 32; off > 0; off >>= 1) sum += __shfl_down(sum, off, 64);
    if ((t & 63) == 0) sh[t >> 6] = sum;
    __syncthreads();
    if (t == 0) {
        float tot = 0.f;
        #pragma unroll
        for (int i = 0; i < 8; ++i) tot += sh[i];
        stat[0] = tot / (float)TOT;
    }
    __syncthreads();

    const float mu = stat[0];
    float sq = 0.f;
    for (int r = 0; r < nv; ++r) { float d = v[r] - mu; sq += d * d; }
    #pragma unroll
    for (int off = 32; off > 0; off >>= 1) sq += __shfl_down(sq, off, 64);
    if ((t & 63) == 0) sh[t >> 6] = sq;   // safe: prior sync ordered t0's reads
    __syncthreads();
    if (t == 0) {
        float tot = 0.f;
        #pragma unroll
        for (int i = 0; i < 8; ++i) tot += sh[i];
        float var = tot / (float)TOT;
        stat[1] = rsqrtf(var + 1e-5f) * bnw[0];
    }
    __syncthreads();

    const float scale = stat[1];
    const float bias  = bnb[0];
    int r = 0;
    for (int idx = t; idx < TOT; idx += 512) {
        out[idx] = (v[r++] - mu) * scale + bias;
    }
}

extern "C" void kernel_launch(void* const* d_in, const int* in_sizes, int n_in,
                              void* d_out, int out_size, void* d_ws, size_t ws_size,
                              hipStream_t stream) {
    const float* z   = (const float*)d_in[0];   // [16,256,6,6]
    const float* x   = (const float*)d_in[1];   // [16,256,22,22]
    const float* w   = (const float*)d_in[2];   // [1,256,1,1,1] -> 256
    const float* bnw = (const float*)d_in[3];   // [1]
    const float* bnb = (const float*)d_in[4];   // [1]
    float* out = (float*)d_out;                 // [16,1,17,17] -> 4624
    float* acc = (float*)d_ws;                  // 4624 floats of scratch

    // ws is poisoned 0xAA before every launch — zero the accumulator.
    hipMemsetAsync(acc, 0, TOT * sizeof(float), stream);

    corr_kernel<<<NB * CGRP, 256, 0, stream>>>(z, x, w, acc);
    bn_kernel<<<1, 512, 0, stream>>>(acc, bnw, bnb, out);
}

// Round 2
// 81.419 us; speedup vs baseline: 1.0254x; 1.0254x over previous
//
#include <hip/hip_runtime.h>

// Problem constants: N=16, C=256, K=6, M=22, Ho=17
#define NB   16
#define CC   256
#define KK   6
#define MM   22
#define HO   17           // M - K + 1
#define NPQ  (HO*HO)      // 289 outputs per batch image
#define TOT  (NB*NPQ)     // 4624 total outputs
#define CHN  8            // channels per block in corr kernel
#define CGRP (CC/CHN)     // 32 channel-groups
#define XPC  (MM*MM)      // 484 x-elements per channel
#define ZPC  (KK*KK)      // 36 z-elements per channel
#define XSTR 24           // padded LDS row stride (22 -> 24, 16B-aligned rows)
#define XCH  548          // padded LDS channel stride: 22*24=528 +20 so stride%32==4 (bank spread), %4==0 (16B align)
#define RCH  292          // reduction buffer channel stride: 289+3, %32==4

// Kernel A: per-(batch, channel-group) correlation, register-tiled.
// Thread t<136 owns one (p-row, channel): 17 outputs, 612 FMAs, 45 LDS b128 reads.
__global__ __launch_bounds__(256) void corr_kernel(
    const float* __restrict__ z, const float* __restrict__ x,
    const float* __restrict__ w, float* __restrict__ part)
{
    __shared__ float szw[CHN * ZPC];    // w_c * sqrt(z)   (288 floats)
    __shared__ float sx [CHN * XCH];    // sqrt(x), padded (17.5 KB)
    __shared__ float red[CHN * RCH];    // per-channel row results

    const int b  = blockIdx.x;
    const int n  = b >> 5;              // / CGRP
    const int cg = b & 31;              // % CGRP
    const int c0 = cg * CHN;
    const int t  = threadIdx.x;

    const float* zb = z + (size_t)(n * CC + c0) * ZPC;
    const float* xb = x + (size_t)(n * CC + c0) * XPC;

    // Stage w*sqrt(z): 288 contiguous floats
    for (int e = t; e < CHN * ZPC; e += 256) {
        int c = e / ZPC;
        szw[e] = sqrtf(zb[e]) * w[c0 + c];
    }
    // Stage sqrt(x) into padded rows; float2 is the widest aligned unit
    // (odd global rows are only 8B-aligned: row stride 22 floats).
    {
        const float2* xb2 = reinterpret_cast<const float2*>(xb);
        for (int e = t; e < CHN * XPC / 2; e += 256) {   // 1936 float2
            int ch  = e / 242;                            // 242 float2/channel
            int r   = e - ch * 242;
            int row = r / 11;
            int col = (r - row * 11) * 2;
            float2 v = xb2[e];
            float* dst = &sx[ch * XCH + row * XSTR + col];
            dst[0] = sqrtf(v.x);
            dst[1] = sqrtf(v.y);
        }
    }
    __syncthreads();

    if (t < HO * CHN) {                 // 136 active threads
        const int p  = t >> 3;          // 0..16
        const int ch = t & 7;           // lanes cycle ch fast -> z b128 conflict-free

        // z fragment -> registers (9 b128, 16B-aligned: 36 floats/channel)
        float zr[36];
        const float4* z4 = reinterpret_cast<const float4*>(&szw[ch * ZPC]);
        #pragma unroll
        for (int k = 0; k < 9; ++k) {
            float4 v = z4[k];
            zr[4*k] = v.x; zr[4*k+1] = v.y; zr[4*k+2] = v.z; zr[4*k+3] = v.w;
        }

        float acc[HO];
        #pragma unroll
        for (int q = 0; q < HO; ++q) acc[q] = 0.f;

        #pragma unroll
        for (int i = 0; i < KK; ++i) {
            // one padded x row -> registers (6 b128); xr[22..23] unused pad
            float xr[24];
            const float4* row4 =
                reinterpret_cast<const float4*>(&sx[ch * XCH + (p + i) * XSTR]);
            #pragma unroll
            for (int k = 0; k < 6; ++k) {
                float4 v = row4[k];
                xr[4*k] = v.x; xr[4*k+1] = v.y; xr[4*k+2] = v.z; xr[4*k+3] = v.w;
            }
            #pragma unroll
            for (int j = 0; j < KK; ++j) {
                float zv = zr[i * KK + j];
                #pragma unroll
                for (int q = 0; q < HO; ++q)
                    acc[q] += zv * xr[q + j];
            }
        }
        float* rr = &red[ch * RCH + p * HO];
        #pragma unroll
        for (int q = 0; q < HO; ++q) rr[q] = acc[q];
    }
    __syncthreads();

    // Sum the 8 channels; write per-channel-group partial (coalesced, no atomics)
    float* pb = part + (size_t)(cg * NB + n) * NPQ;
    for (int idx = t; idx < NPQ; idx += 256) {
        float s = 0.f;
        #pragma unroll
        for (int ch = 0; ch < CHN; ++ch) s += red[ch * RCH + idx];
        pb[idx] = s;
    }
}

// Kernel B: sum 32 channel-group partials + global BatchNorm (two-pass) + write.
__global__ __launch_bounds__(512) void bn_kernel(
    const float* __restrict__ part, const float* __restrict__ bnw,
    const float* __restrict__ bnb, float* __restrict__ out)
{
    __shared__ float sh[8];
    __shared__ float stat[2];
    const int t = threadIdx.x;

    float v[10];
    int nv = 0;
    float sum = 0.f;
    for (int idx = t; idx < TOT; idx += 512) {
        float s = 0.f;
        #pragma unroll
        for (int cg = 0; cg < CGRP; ++cg) s += part[(size_t)cg * TOT + idx];
        float val = s * (1.0f / 36.0f);
        v[nv++] = val;
        sum += val;
    }
    #pragma unroll
    for (int off = 32; off > 0; off >>= 1) sum += __shfl_down(sum, off, 64);
    if ((t & 63) == 0) sh[t >> 6] = sum;
    __syncthreads();
    if (t == 0) {
        float tot = 0.f;
        #pragma unroll
        for (int i = 0; i < 8; ++i) tot += sh[i];
        stat[0] = tot / (float)TOT;
    }
    __syncthreads();

    const float mu = stat[0];
    float sq = 0.f;
    for (int r = 0; r < nv; ++r) { float d = v[r] - mu; sq += d * d; }
    #pragma unroll
    for (int off = 32; off > 0; off >>= 1) sq += __shfl_down(sq, off, 64);
    if ((t & 63) == 0) sh[t >> 6] = sq;
    __syncthreads();
    if (t == 0) {
        float tot = 0.f;
        #pragma unroll
        for (int i = 0; i < 8; ++i) tot += sh[i];
        float var = tot / (float)TOT;
        stat[1] = rsqrtf(var + 1e-5f) * bnw[0];
    }
    __syncthreads();

    const float scale = stat[1];
    const float bias  = bnb[0];
    int r = 0;
    for (int idx = t; idx < TOT; idx += 512) {
        out[idx] = (v[r++] - mu) * scale + bias;
    }
}

extern "C" void kernel_launch(void* const* d_in, const int* in_sizes, int n_in,
                              void* d_out, int out_size, void* d_ws, size_t ws_size,
                              hipStream_t stream) {
    const float* z   = (const float*)d_in[0];   // [16,256,6,6]
    const float* x   = (const float*)d_in[1];   // [16,256,22,22]
    const float* w   = (const float*)d_in[2];   // [1,256,1,1,1] -> 256
    const float* bnw = (const float*)d_in[3];   // [1]
    const float* bnb = (const float*)d_in[4];   // [1]
    float* out  = (float*)d_out;                // [16,1,17,17] -> 4624
    float* part = (float*)d_ws;                 // [32][16][289] partials (written before read; no memset needed)

    corr_kernel<<<NB * CGRP, 256, 0, stream>>>(z, x, w, part);
    bn_kernel<<<1, 512, 0, stream>>>(part, bnw, bnb, out);
}